// Round 2
// baseline (120.610 us; speedup 1.0000x reference)
//
#include <hip/hip_runtime.h>
#include <stdint.h>

// Problem constants (match reference)
#define BB 4
#define NN 16384
#define SS 4096
#define CC 64
#define KK 32

// ws layout:
//   [0, BB*NN*16)                       packed float4 {x,y,z,0}
//   [BB*NN*16, + BB*SS*KK*4)            idx int32
#define PACKED_BYTES ((size_t)BB * NN * sizeof(float4))

// ---------------------------------------------------------------------------
// Kernel 0: pack xyz -> float4 {x,y,z,0} for aligned 16B loads in ball query.
// ---------------------------------------------------------------------------
__global__ __launch_bounds__(256) void pack_kernel(const float* __restrict__ xyz,
                                                   float4* __restrict__ packed) {
    int i = blockIdx.x * blockDim.x + threadIdx.x;
    if (i >= BB * NN) return;
    float x = xyz[(size_t)i * 3 + 0];
    float y = xyz[(size_t)i * 3 + 1];
    float z = xyz[(size_t)i * 3 + 2];
    packed[i] = make_float4(x, y, z, 0.0f);
}

// ---------------------------------------------------------------------------
// Kernel 1: ball query — one wave (64 lanes) per centroid, exact early exit.
// Distance computed in DOUBLE precision: f32 inputs are exact in f64, so d2
// is exact to ~1e-16 regardless of op order -> matches a float64 numpy
// reference on every boundary decision.
// Semantics: first KK indices (ascending) with d2 < 0.2*0.2; remaining slots
// filled with first found index (0 if none).
// ---------------------------------------------------------------------------
__global__ __launch_bounds__(256) void ballq_kernel(const float4* __restrict__ packed,
                                                    const float* __restrict__ new_xyz,
                                                    int* __restrict__ idx) {
    int wid  = (int)((blockIdx.x * blockDim.x + threadIdx.x) >> 6);  // centroid id
    int lane = (int)(threadIdx.x & 63);
    int b = wid >> 12;          // / SS   (SS = 4096)
    int s = wid & (SS - 1);

    const float* nc = new_xyz + (size_t)(b * SS + s) * 3;
    const double nx = (double)nc[0], ny = (double)nc[1], nz = (double)nc[2];
    const double t1 = nx * nx + ny * ny + nz * nz;
    const double r2 = 0.2 * 0.2;   // double(0.2)^2, matches np RADIUS*RADIUS

    const float4* pts = packed + (size_t)b * NN;
    int* out = idx + (size_t)wid * KK;

    int cnt = 0;
    int first = 0;

    for (int base = 0; base < NN; base += 64) {
        float4 p = pts[base + lane];
        double px = (double)p.x, py = (double)p.y, pz = (double)p.z;
        double t2  = px * px + py * py + pz * pz;
        double dot = nx * px + ny * py + nz * pz;
        double d2  = (t1 + t2) - 2.0 * dot;
        bool inb = d2 < r2;
        unsigned long long mask = __ballot(inb);
        if (cnt == 0 && mask != 0ull)
            first = base + (int)__builtin_ctzll(mask);
        if (inb) {
            unsigned long long lt = mask & ((1ull << lane) - 1ull);
            int slot = cnt + (int)__popcll(lt);
            if (slot < KK) out[slot] = base + lane;
        }
        cnt += (int)__popcll(mask);
        if (cnt >= KK) break;
    }
    // fill tail slots [cnt, KK) with first-found index (0 if none)
    if (cnt < KK && lane >= cnt && lane < KK) out[lane] = first;
}

// ---------------------------------------------------------------------------
// Kernel 2: group + concat. One thread per (b, s, k/4): handles 4 k-slots,
// loops over the 67 output channels. Stores are float4, coalesced per wave.
// out[b, 0:3, s, k]  = xyz[b, idx, :] - new_xyz[b, s, :]
// out[b, 3:67, s, k] = features[b, :, idx]
// ---------------------------------------------------------------------------
__global__ __launch_bounds__(256) void group_kernel(const float4* __restrict__ packed,
                                                    const float* __restrict__ new_xyz,
                                                    const float* __restrict__ features,
                                                    const int* __restrict__ idx,
                                                    float* __restrict__ out) {
    int t = blockIdx.x * blockDim.x + threadIdx.x;   // 0 .. BB*SS*8
    int b   = t >> 15;                // / (SS*8)
    int rem = t & (SS * 8 - 1);
    int s   = rem >> 3;
    int k0  = (rem & 7) << 2;

    const int4 jj = *(const int4*)(idx + (size_t)(b * SS + s) * KK + k0);

    const float* nc = new_xyz + (size_t)(b * SS + s) * 3;
    float ncx = nc[0], ncy = nc[1], ncz = nc[2];

    const float4* pts = packed + (size_t)b * NN;
    float4 p0 = pts[jj.x], p1 = pts[jj.y], p2 = pts[jj.z], p3 = pts[jj.w];

    const size_t cs = (size_t)SS * KK;                       // channel stride
    size_t obase = ((size_t)b * 67) * cs + (size_t)s * KK + k0;

    *(float4*)(out + obase)          = make_float4(p0.x - ncx, p1.x - ncx, p2.x - ncx, p3.x - ncx);
    *(float4*)(out + obase + cs)     = make_float4(p0.y - ncy, p1.y - ncy, p2.y - ncy, p3.y - ncy);
    *(float4*)(out + obase + 2 * cs) = make_float4(p0.z - ncz, p1.z - ncz, p2.z - ncz, p3.z - ncz);

    const float* frow = features + (size_t)b * CC * NN;
    float* ob = out + obase + 3 * cs;
#pragma unroll 4
    for (int c = 0; c < CC; ++c) {
        const float* f = frow + (size_t)c * NN;
        *(float4*)(ob + (size_t)c * cs) = make_float4(f[jj.x], f[jj.y], f[jj.z], f[jj.w]);
    }
}

extern "C" void kernel_launch(void* const* d_in, const int* in_sizes, int n_in,
                              void* d_out, int out_size, void* d_ws, size_t ws_size,
                              hipStream_t stream) {
    const float* xyz      = (const float*)d_in[0];   // [B,N,3]
    const float* new_xyz  = (const float*)d_in[1];   // [B,S,3]
    const float* features = (const float*)d_in[2];   // [B,C,N]
    float* out = (float*)d_out;                      // [B,67,S,K]

    float4* packed = (float4*)d_ws;
    int*    idx    = (int*)((char*)d_ws + PACKED_BYTES);

    // Kernel 0: pack points
    {
        int total = BB * NN;
        pack_kernel<<<(total + 255) / 256, 256, 0, stream>>>(xyz, packed);
    }
    // Kernel 1: ball query — one wave per centroid, 4 waves per block
    {
        int waves = BB * SS;
        ballq_kernel<<<waves / 4, 256, 0, stream>>>(packed, new_xyz, idx);
    }
    // Kernel 2: group + concat
    {
        int threads = BB * SS * 8;
        group_kernel<<<threads / 256, 256, 0, stream>>>(packed, new_xyz, features, idx, out);
    }
}

// Round 3
// 93.641 us; speedup vs baseline: 1.2880x; 1.2880x over previous
//
#include <hip/hip_runtime.h>
#include <stdint.h>

// Problem constants (match reference)
#define BB 4
#define NN 16384
#define SS 4096
#define CC 64
#define KK 32

// ws layout:
//   [0, BB*NN*16)                       packed float4 {x,y,z,0}
//   [BB*NN*16, + BB*SS*KK*4)            idx int32
#define PACKED_BYTES ((size_t)BB * NN * sizeof(float4))

// ---------------------------------------------------------------------------
// Kernel 0: pack xyz -> float4 {x,y,z,0} for aligned 16B loads in ball query.
// ---------------------------------------------------------------------------
__global__ __launch_bounds__(256) void pack_kernel(const float* __restrict__ xyz,
                                                   float4* __restrict__ packed) {
    int i = blockIdx.x * blockDim.x + threadIdx.x;
    if (i >= BB * NN) return;
    float x = xyz[(size_t)i * 3 + 0];
    float y = xyz[(size_t)i * 3 + 1];
    float z = xyz[(size_t)i * 3 + 2];
    packed[i] = make_float4(x, y, z, 0.0f);
}

// ---------------------------------------------------------------------------
// Kernel 1: ball query — one wave (64 lanes) per centroid, exact early exit.
// DOUBLE-precision distances: matches the float64 numpy reference exactly
// (verified R2: absmax 0.0).
// ---------------------------------------------------------------------------
__global__ __launch_bounds__(256) void ballq_kernel(const float4* __restrict__ packed,
                                                    const float* __restrict__ new_xyz,
                                                    int* __restrict__ idx) {
    int wid  = (int)((blockIdx.x * blockDim.x + threadIdx.x) >> 6);  // centroid id
    int lane = (int)(threadIdx.x & 63);
    int b = wid >> 12;          // / SS   (SS = 4096)
    int s = wid & (SS - 1);

    const float* nc = new_xyz + (size_t)(b * SS + s) * 3;
    const double nx = (double)nc[0], ny = (double)nc[1], nz = (double)nc[2];
    const double t1 = nx * nx + ny * ny + nz * nz;
    const double r2 = 0.2 * 0.2;

    const float4* pts = packed + (size_t)b * NN;
    int* out = idx + (size_t)wid * KK;

    int cnt = 0;
    int first = 0;

    for (int base = 0; base < NN; base += 64) {
        float4 p = pts[base + lane];
        double px = (double)p.x, py = (double)p.y, pz = (double)p.z;
        double t2  = px * px + py * py + pz * pz;
        double dot = nx * px + ny * py + nz * pz;
        double d2  = (t1 + t2) - 2.0 * dot;
        bool inb = d2 < r2;
        unsigned long long mask = __ballot(inb);
        if (cnt == 0 && mask != 0ull)
            first = base + (int)__builtin_ctzll(mask);
        if (inb) {
            unsigned long long lt = mask & ((1ull << lane) - 1ull);
            int slot = cnt + (int)__popcll(lt);
            if (slot < KK) out[slot] = base + lane;
        }
        cnt += (int)__popcll(mask);
        if (cnt >= KK) break;
    }
    if (cnt < KK && lane >= cnt && lane < KK) out[lane] = first;
}

// ---------------------------------------------------------------------------
// Kernel 2: group + concat — one thread per (b, ch, s, k/4).
// grid = B*67*(S/32) blocks of 256; block-uniform channel -> no divergence.
// Wave: 1 KB contiguous store, 1 KB contiguous idx load, 256 L2-resident
// gathers. 34304 blocks -> full occupancy (vs R2's 512-block latency bind).
// ---------------------------------------------------------------------------
__global__ __launch_bounds__(256) void group_kernel(const float4* __restrict__ packed,
                                                    const float* __restrict__ new_xyz,
                                                    const float* __restrict__ features,
                                                    const int* __restrict__ idx,
                                                    float* __restrict__ out) {
    int bc = blockIdx.x >> 7;           // b*67 + ch
    int s5 = blockIdx.x & 127;          // s / 32
    int b  = bc / 67;
    int ch = bc - b * 67;
    int s  = (s5 << 5) | ((int)threadIdx.x >> 3);
    int k0 = ((int)threadIdx.x & 7) << 2;

    const int4 jj = *(const int4*)(idx + ((size_t)(b * SS + s) * KK + k0));
    size_t oaddr = ((size_t)bc * SS + s) * KK + k0;

    float4 r;
    if (ch < 3) {
        const float4* pts = packed + (size_t)b * NN;
        float4 p0 = pts[jj.x], p1 = pts[jj.y], p2 = pts[jj.z], p3 = pts[jj.w];
        float nc = new_xyz[(size_t)(b * SS + s) * 3 + ch];
        float a0, a1, a2, a3;
        if (ch == 0)      { a0 = p0.x; a1 = p1.x; a2 = p2.x; a3 = p3.x; }
        else if (ch == 1) { a0 = p0.y; a1 = p1.y; a2 = p2.y; a3 = p3.y; }
        else              { a0 = p0.z; a1 = p1.z; a2 = p2.z; a3 = p3.z; }
        r = make_float4(a0 - nc, a1 - nc, a2 - nc, a3 - nc);
    } else {
        const float* f = features + ((size_t)b * CC + (ch - 3)) * NN;
        r = make_float4(f[jj.x], f[jj.y], f[jj.z], f[jj.w]);
    }
    *(float4*)(out + oaddr) = r;
}

extern "C" void kernel_launch(void* const* d_in, const int* in_sizes, int n_in,
                              void* d_out, int out_size, void* d_ws, size_t ws_size,
                              hipStream_t stream) {
    const float* xyz      = (const float*)d_in[0];   // [B,N,3]
    const float* new_xyz  = (const float*)d_in[1];   // [B,S,3]
    const float* features = (const float*)d_in[2];   // [B,C,N]
    float* out = (float*)d_out;                      // [B,67,S,K]

    float4* packed = (float4*)d_ws;
    int*    idx    = (int*)((char*)d_ws + PACKED_BYTES);

    // Kernel 0: pack points
    {
        int total = BB * NN;
        pack_kernel<<<(total + 255) / 256, 256, 0, stream>>>(xyz, packed);
    }
    // Kernel 1: ball query — one wave per centroid, 4 waves per block
    {
        int waves = BB * SS;
        ballq_kernel<<<waves / 4, 256, 0, stream>>>(packed, new_xyz, idx);
    }
    // Kernel 2: group + concat — one thread per (b, ch, s, k/4)
    {
        int blocks = BB * 67 * (SS / 32);   // 34304
        group_kernel<<<blocks, 256, 0, stream>>>(packed, new_xyz, features, idx, out);
    }
}

// Round 4
// 87.691 us; speedup vs baseline: 1.3754x; 1.0678x over previous
//
#include <hip/hip_runtime.h>
#include <stdint.h>

// Problem constants (match reference)
#define BB 4
#define NN 16384
#define SS 4096
#define CC 64
#define KK 32
#define R2F 0.04f
#define EPSF 1e-5f   // f32 screening band; f32 abs err bound ~2e-6, 5x margin

// ws layout:
//   [0, 1MB)    packed float4 {x,y,z,0}
//   [1MB, 3MB)  idx int32 [B,S,K]
//   [3MB, 19MB) featT float [B,N,C]  (features transposed)
#define PACKED_BYTES ((size_t)BB * NN * sizeof(float4))
#define IDX_BYTES    ((size_t)BB * SS * KK * sizeof(int))
#define FEATT_BYTES  ((size_t)BB * NN * CC * sizeof(float))

// ---------------------------------------------------------------------------
// Kernel 0: pack xyz -> float4 {x,y,z,0}
// ---------------------------------------------------------------------------
__global__ __launch_bounds__(256) void pack_kernel(const float* __restrict__ xyz,
                                                   float4* __restrict__ packed) {
    int i = blockIdx.x * blockDim.x + threadIdx.x;
    if (i >= BB * NN) return;
    float x = xyz[(size_t)i * 3 + 0];
    float y = xyz[(size_t)i * 3 + 1];
    float z = xyz[(size_t)i * 3 + 2];
    packed[i] = make_float4(x, y, z, 0.0f);
}

// ---------------------------------------------------------------------------
// Kernel 0b: transpose features [B,C,N] -> featT [B,N,C].
// Block = (b, 64-wide n tile). Stores: float4 along c, lanes cover 4 n rows
// x full 64 c = 4x256B contiguous segments. Loads: 4 scattered dwords/thread,
// but every dword of the 16KB tile is read exactly once per block (L1 reuse).
// ---------------------------------------------------------------------------
__global__ __launch_bounds__(256) void transpose_kernel(const float* __restrict__ features,
                                                        float* __restrict__ featT) {
    int blk = blockIdx.x;
    int b   = blk >> 8;              // NN/64 = 256 tiles per b
    int n0  = (blk & 255) << 6;
    const float* f = features + (size_t)b * CC * NN;
    for (int i = 0; i < 4; ++i) {
        int e  = (int)threadIdx.x + i * 256;   // 0..1023
        int c4 = e & 15;
        int n  = n0 + (e >> 4);
        float4 v;
        v.x = f[(size_t)(c4 * 4 + 0) * NN + n];
        v.y = f[(size_t)(c4 * 4 + 1) * NN + n];
        v.z = f[(size_t)(c4 * 4 + 2) * NN + n];
        v.w = f[(size_t)(c4 * 4 + 3) * NN + n];
        *(float4*)(featT + ((size_t)b * NN + n) * CC + c4 * 4) = v;
    }
}

// ---------------------------------------------------------------------------
// Kernel 1: ball query — one wave per centroid, exact early exit.
// f32 FMA screen; only |d2f - R2| < EPSF lanes recheck in exact f64
// (f64 decisions == float64 numpy reference; verified absmax 0.0 in R2/R3).
// ---------------------------------------------------------------------------
__global__ __launch_bounds__(256) void ballq_kernel(const float4* __restrict__ packed,
                                                    const float* __restrict__ new_xyz,
                                                    int* __restrict__ idx) {
    int wid  = (int)((blockIdx.x * blockDim.x + threadIdx.x) >> 6);  // centroid id
    int lane = (int)(threadIdx.x & 63);
    int b = wid >> 12;
    int s = wid & (SS - 1);

    const float* nc = new_xyz + (size_t)(b * SS + s) * 3;
    const float nxf = nc[0], nyf = nc[1], nzf = nc[2];
    const float t1f = fmaf(nzf, nzf, fmaf(nyf, nyf, nxf * nxf));
    const double nx = (double)nxf, ny = (double)nyf, nz = (double)nzf;
    const double t1 = nx * nx + ny * ny + nz * nz;
    const double r2 = 0.2 * 0.2;

    const float4* pts = packed + (size_t)b * NN;
    int* out = idx + (size_t)wid * KK;

    int cnt = 0;
    int first = 0;

    for (int base = 0; base < NN; base += 64) {
        float4 p = pts[base + lane];
        float dotf = fmaf(nzf, p.z, fmaf(nyf, p.y, nxf * p.x));
        float t2f  = fmaf(p.z, p.z, fmaf(p.y, p.y, p.x * p.x));
        float d2f  = (t1f + t2f) - 2.0f * dotf;
        bool inb;
        if (__builtin_fabsf(d2f - R2F) < EPSF) {
            // borderline (~1e-5 of pairs): exact f64 decision
            double px = (double)p.x, py = (double)p.y, pz = (double)p.z;
            double t2  = px * px + py * py + pz * pz;
            double dot = nx * px + ny * py + nz * pz;
            inb = ((t1 + t2) - 2.0 * dot) < r2;
        } else {
            inb = d2f < R2F;
        }
        unsigned long long mask = __ballot(inb);
        if (cnt == 0 && mask != 0ull)
            first = base + (int)__builtin_ctzll(mask);
        if (inb) {
            unsigned long long lt = mask & ((1ull << lane) - 1ull);
            int slot = cnt + (int)__popcll(lt);
            if (slot < KK) out[slot] = base + lane;
        }
        cnt += (int)__popcll(mask);
        if (cnt >= KK) break;
    }
    if (cnt < KK && lane >= cnt && lane < KK) out[lane] = first;
}

// ---------------------------------------------------------------------------
// Kernel 2 (fast): group + concat — one block per (b,s).
// Stage the 32 gathered featT rows (256B each, fully-utilized lines) into
// XOR-swizzled LDS, then write 67x32 outputs k-contiguous (coalesced).
// XCD swizzle: 16384 blocks, chunk 2048 -> XCD x reads only featT[x/2]
// (4 MB = one XCD L2).
// ---------------------------------------------------------------------------
__global__ __launch_bounds__(256) void group_fast_kernel(const float4* __restrict__ packed,
                                                         const float* __restrict__ new_xyz,
                                                         const float* __restrict__ featT,
                                                         const int* __restrict__ idx,
                                                         float* __restrict__ out) {
    __shared__ float4 sfeat[32][16];  // [point][col4 ^ (point&15)]
    __shared__ float  sxyz[3][32];
    __shared__ int    sidx[32];

    int bid  = blockIdx.x;
    int wgid = (bid & 7) * 2048 + (bid >> 3);   // bijective: 16384 % 8 == 0
    int b = wgid >> 12;
    int s = wgid & (SS - 1);
    int t = (int)threadIdx.x;

    if (t < 32) {
        int j = idx[((size_t)(b * SS + s)) * KK + t];
        sidx[t] = j;
        float4 pnt = packed[(size_t)b * NN + j];
        sxyz[0][t] = pnt.x; sxyz[1][t] = pnt.y; sxyz[2][t] = pnt.z;
    }
    __syncthreads();

    // stage features: 8 threads per point, 32B each (2 x float4), coalesced
    {
        int p = t >> 3, q = t & 7;
        const float4* src = (const float4*)(featT + ((size_t)b * NN + sidx[p]) * CC);
        float4 v0 = src[q * 2];
        float4 v1 = src[q * 2 + 1];
        sfeat[p][(q * 2)     ^ (p & 15)] = v0;
        sfeat[p][(q * 2 + 1) ^ (p & 15)] = v1;
    }
    __syncthreads();

    const size_t cs = (size_t)SS * KK;
    size_t obase = (size_t)(b * 67) * cs + (size_t)s * KK;

    // xyz channels (3 x 32)
    if (t < 96) {
        int ch = t >> 5, k = t & 31;
        float ncv = new_xyz[((size_t)(b * SS + s)) * 3 + ch];
        out[obase + (size_t)ch * cs + k] = sxyz[ch][k] - ncv;
    }
    // feature channels (64 x 32): half-wave = 32 consecutive k -> coalesced
    for (int i = 0; i < 8; ++i) {
        int e  = t + i * 256;       // 0..2047
        int ch = e >> 5, k = e & 31;
        int c4 = ch >> 2, cj = ch & 3;
        float v = ((const float*)&sfeat[k][c4 ^ (k & 15)])[cj];
        out[obase + (size_t)(3 + ch) * cs + k] = v;
    }
}

// ---------------------------------------------------------------------------
// Kernel 2 (fallback, R3-style) if ws too small for featT
// ---------------------------------------------------------------------------
__global__ __launch_bounds__(256) void group_kernel(const float4* __restrict__ packed,
                                                    const float* __restrict__ new_xyz,
                                                    const float* __restrict__ features,
                                                    const int* __restrict__ idx,
                                                    float* __restrict__ out) {
    int bc = blockIdx.x >> 7;
    int s5 = blockIdx.x & 127;
    int b  = bc / 67;
    int ch = bc - b * 67;
    int s  = (s5 << 5) | ((int)threadIdx.x >> 3);
    int k0 = ((int)threadIdx.x & 7) << 2;

    const int4 jj = *(const int4*)(idx + ((size_t)(b * SS + s) * KK + k0));
    size_t oaddr = ((size_t)bc * SS + s) * KK + k0;

    float4 r;
    if (ch < 3) {
        const float4* pts = packed + (size_t)b * NN;
        float4 p0 = pts[jj.x], p1 = pts[jj.y], p2 = pts[jj.z], p3 = pts[jj.w];
        float nc = new_xyz[(size_t)(b * SS + s) * 3 + ch];
        float a0, a1, a2, a3;
        if (ch == 0)      { a0 = p0.x; a1 = p1.x; a2 = p2.x; a3 = p3.x; }
        else if (ch == 1) { a0 = p0.y; a1 = p1.y; a2 = p2.y; a3 = p3.y; }
        else              { a0 = p0.z; a1 = p1.z; a2 = p2.z; a3 = p3.z; }
        r = make_float4(a0 - nc, a1 - nc, a2 - nc, a3 - nc);
    } else {
        const float* f = features + ((size_t)b * CC + (ch - 3)) * NN;
        r = make_float4(f[jj.x], f[jj.y], f[jj.z], f[jj.w]);
    }
    *(float4*)(out + oaddr) = r;
}

extern "C" void kernel_launch(void* const* d_in, const int* in_sizes, int n_in,
                              void* d_out, int out_size, void* d_ws, size_t ws_size,
                              hipStream_t stream) {
    const float* xyz      = (const float*)d_in[0];   // [B,N,3]
    const float* new_xyz  = (const float*)d_in[1];   // [B,S,3]
    const float* features = (const float*)d_in[2];   // [B,C,N]
    float* out = (float*)d_out;                      // [B,67,S,K]

    float4* packed = (float4*)d_ws;
    int*    idx    = (int*)((char*)d_ws + PACKED_BYTES);
    float*  featT  = (float*)((char*)d_ws + PACKED_BYTES + IDX_BYTES);

    bool fast = ws_size >= PACKED_BYTES + IDX_BYTES + FEATT_BYTES;

    pack_kernel<<<(BB * NN + 255) / 256, 256, 0, stream>>>(xyz, packed);
    if (fast)
        transpose_kernel<<<BB * (NN / 64), 256, 0, stream>>>(features, featT);
    ballq_kernel<<<(BB * SS) / 4, 256, 0, stream>>>(packed, new_xyz, idx);
    if (fast) {
        group_fast_kernel<<<BB * SS, 256, 0, stream>>>(packed, new_xyz, featT, idx, out);
    } else {
        group_kernel<<<BB * 67 * (SS / 32), 256, 0, stream>>>(packed, new_xyz, features, idx, out);
    }
}

// Round 5
// 68.066 us; speedup vs baseline: 1.7720x; 1.2883x over previous
//
#include <hip/hip_runtime.h>
#include <stdint.h>

// Problem constants (match reference)
#define BB 4
#define NN 16384
#define SS 4096
#define CC 64
#define KK 32
#define R2F 0.04f
#define EPSF 1e-5f   // f32 screening band; f32 abs err bound ~2e-6, 5x margin

// ws layout:
//   [0, 1MB)    packed float4 {x,y,z,0}
//   [1MB, 3MB)  idx int32 [B,S,K]        (fallback path only)
//   [3MB, 19MB) featT float [B,N,C]
#define PACKED_BYTES ((size_t)BB * NN * sizeof(float4))
#define IDX_BYTES    ((size_t)BB * SS * KK * sizeof(int))
#define FEATT_BYTES  ((size_t)BB * NN * CC * sizeof(float))

// ---------------------------------------------------------------------------
// Kernel 0: prep = pack (blocks 0..63) + transpose (blocks 64..1087).
// pack: xyz -> float4 {x,y,z,0}.
// transpose: features [B,C,N] -> featT [B,N,C]; per block one (b, 64-n tile),
// 16KB tile reused from L1, stores are 256B-contiguous float4 runs.
// ---------------------------------------------------------------------------
__global__ __launch_bounds__(256) void prep_kernel(const float* __restrict__ xyz,
                                                   const float* __restrict__ features,
                                                   float4* __restrict__ packed,
                                                   float* __restrict__ featT) {
    int blk = blockIdx.x;
    if (blk < 64) {
        // pack: 64 blocks x 256 threads x 4 points
        for (int i = 0; i < 4; ++i) {
            int p = blk * 1024 + i * 256 + (int)threadIdx.x;
            float x = xyz[(size_t)p * 3 + 0];
            float y = xyz[(size_t)p * 3 + 1];
            float z = xyz[(size_t)p * 3 + 2];
            packed[p] = make_float4(x, y, z, 0.0f);
        }
        return;
    }
    blk -= 64;
    int b  = blk >> 8;               // NN/64 = 256 tiles per b
    int n0 = (blk & 255) << 6;
    const float* f = features + (size_t)b * CC * NN;
    for (int i = 0; i < 4; ++i) {
        int e  = (int)threadIdx.x + i * 256;   // 0..1023
        int c4 = e & 15;
        int n  = n0 + (e >> 4);
        float4 v;
        v.x = f[(size_t)(c4 * 4 + 0) * NN + n];
        v.y = f[(size_t)(c4 * 4 + 1) * NN + n];
        v.z = f[(size_t)(c4 * 4 + 2) * NN + n];
        v.w = f[(size_t)(c4 * 4 + 3) * NN + n];
        *(float4*)(featT + ((size_t)b * NN + n) * CC + c4 * 4) = v;
    }
}

// ---------------------------------------------------------------------------
// Kernel 1 (fused): ball query + group + concat. One block (4 waves) per
// centroid (b,s).
// Phase A: cooperative ordered scan, 256 points per super-chunk. Each wave
//   ballots its 64 points; masks exchanged via double-buffered LDS (one
//   barrier per iter); cross-wave prefix -> exact first-KK-in-index-order.
//   Selected idx + xyz go straight to LDS. f32 FMA screen with f64 recheck
//   for |d2-R2|<EPS keeps decisions bit-identical to the f64 numpy ref.
// Phase B: stage 32 featT rows (256B each, fully-dense lines) into
//   XOR-swizzled LDS; write 67x32 outputs as float4, dense per wave.
// XCD swizzle (16384 % 8 == 0, bijective): XCD x reads only featT[x/2]
// (4MB = one XCD L2).
// ---------------------------------------------------------------------------
__global__ __launch_bounds__(256) void fused_kernel(const float4* __restrict__ packed,
                                                    const float* __restrict__ new_xyz,
                                                    const float* __restrict__ featT,
                                                    float* __restrict__ out) {
    __shared__ unsigned long long smask[2][4];
    __shared__ int    sidx[KK];
    __shared__ float  sxyz[3][KK];
    __shared__ float4 sfeat[KK][16];   // [point][col4 ^ (point&15)]

    int bid  = blockIdx.x;
    int wgid = (bid & 7) * 2048 + (bid >> 3);   // bijective XCD chunking
    int b = wgid >> 12;
    int s = wgid & (SS - 1);
    int t = (int)threadIdx.x;
    int w = t >> 6, lane = t & 63;

    const float* nc = new_xyz + (size_t)(b * SS + s) * 3;
    const float nxf = nc[0], nyf = nc[1], nzf = nc[2];
    const float t1f = fmaf(nzf, nzf, fmaf(nyf, nyf, nxf * nxf));
    const double nx = (double)nxf, ny = (double)nyf, nz = (double)nzf;
    const double t1 = nx * nx + ny * ny + nz * nz;
    const double r2 = 0.2 * 0.2;

    const float4* pts = packed + (size_t)b * NN;

    int CNT = 0;
    int first = 0;
    for (int sc = 0; sc < NN / 256; ++sc) {
        int j = sc * 256 + w * 64 + lane;
        float4 p = pts[j];
        float dotf = fmaf(nzf, p.z, fmaf(nyf, p.y, nxf * p.x));
        float t2f  = fmaf(p.z, p.z, fmaf(p.y, p.y, p.x * p.x));
        float d2f  = (t1f + t2f) - 2.0f * dotf;
        bool inb;
        if (__builtin_fabsf(d2f - R2F) < EPSF) {
            double px = (double)p.x, py = (double)p.y, pz = (double)p.z;
            double t2  = px * px + py * py + pz * pz;
            double dot = nx * px + ny * py + nz * pz;
            inb = ((t1 + t2) - 2.0 * dot) < r2;
        } else {
            inb = d2f < R2F;
        }
        unsigned long long mask = __ballot(inb);
        if (lane == 0) smask[sc & 1][w] = mask;
        __syncthreads();
        unsigned long long m0 = smask[sc & 1][0];
        unsigned long long m1 = smask[sc & 1][1];
        unsigned long long m2 = smask[sc & 1][2];
        unsigned long long m3 = smask[sc & 1][3];
        int c0 = (int)__popcll(m0), c1 = (int)__popcll(m1);
        int c2 = (int)__popcll(m2), c3 = (int)__popcll(m3);
        if (CNT == 0) {
            if      (m0) first = sc * 256       + (int)__builtin_ctzll(m0);
            else if (m1) first = sc * 256 + 64  + (int)__builtin_ctzll(m1);
            else if (m2) first = sc * 256 + 128 + (int)__builtin_ctzll(m2);
            else if (m3) first = sc * 256 + 192 + (int)__builtin_ctzll(m3);
        }
        if (inb) {
            int cb = CNT;
            if (w > 0) cb += c0;
            if (w > 1) cb += c1;
            if (w > 2) cb += c2;
            int slot = cb + (int)__popcll(mask & ((1ull << lane) - 1ull));
            if (slot < KK) {
                sidx[slot] = j;
                sxyz[0][slot] = p.x; sxyz[1][slot] = p.y; sxyz[2][slot] = p.z;
            }
        }
        CNT += c0 + c1 + c2 + c3;
        if (CNT >= KK) break;   // uniform across block
    }
    __syncthreads();
    if (t >= CNT && t < KK) {
        float4 p = pts[first];   // broadcast load (same addr)
        sidx[t] = first;
        sxyz[0][t] = p.x; sxyz[1][t] = p.y; sxyz[2][t] = p.z;
    }
    __syncthreads();

    // Phase B1: stage features — 8 threads per point, 2 x float4 (256B/row)
    {
        int p8 = t >> 3, q = t & 7;
        const float4* src = (const float4*)(featT + ((size_t)b * NN + sidx[p8]) * CC);
        float4 v0 = src[q * 2];
        float4 v1 = src[q * 2 + 1];
        sfeat[p8][(q * 2)     ^ (p8 & 15)] = v0;
        sfeat[p8][(q * 2 + 1) ^ (p8 & 15)] = v1;
    }
    __syncthreads();

    // Phase B2: write 536 float4s (67 ch x 8 k-quads), dense per wave
    const size_t cs = (size_t)SS * KK;
    size_t obase = (size_t)(b * 67) * cs + (size_t)s * KK;
    for (int id = t; id < 536; id += 256) {
        int ch = id >> 3, k0 = (id & 7) << 2;
        float4 v;
        if (ch < 3) {
            float ncv = (ch == 0) ? nxf : ((ch == 1) ? nyf : nzf);
            v = make_float4(sxyz[ch][k0] - ncv, sxyz[ch][k0 + 1] - ncv,
                            sxyz[ch][k0 + 2] - ncv, sxyz[ch][k0 + 3] - ncv);
        } else {
            int c = ch - 3, c4 = c >> 2, cj = c & 3;
            v.x = ((const float*)&sfeat[k0    ][c4 ^ ((k0    ) & 15)])[cj];
            v.y = ((const float*)&sfeat[k0 + 1][c4 ^ ((k0 + 1) & 15)])[cj];
            v.z = ((const float*)&sfeat[k0 + 2][c4 ^ ((k0 + 2) & 15)])[cj];
            v.w = ((const float*)&sfeat[k0 + 3][c4 ^ ((k0 + 3) & 15)])[cj];
        }
        *(float4*)(out + obase + (size_t)ch * cs + k0) = v;
    }
}

// ---------------------------------------------------------------------------
// Fallback path (ws too small for featT): R4 kernels
// ---------------------------------------------------------------------------
__global__ __launch_bounds__(256) void ballq_kernel(const float4* __restrict__ packed,
                                                    const float* __restrict__ new_xyz,
                                                    int* __restrict__ idx) {
    int wid  = (int)((blockIdx.x * blockDim.x + threadIdx.x) >> 6);
    int lane = (int)(threadIdx.x & 63);
    int b = wid >> 12;
    int s = wid & (SS - 1);

    const float* nc = new_xyz + (size_t)(b * SS + s) * 3;
    const double nx = (double)nc[0], ny = (double)nc[1], nz = (double)nc[2];
    const double t1 = nx * nx + ny * ny + nz * nz;
    const double r2 = 0.2 * 0.2;

    const float4* pts = packed + (size_t)b * NN;
    int* out = idx + (size_t)wid * KK;

    int cnt = 0;
    int first = 0;
    for (int base = 0; base < NN; base += 64) {
        float4 p = pts[base + lane];
        double px = (double)p.x, py = (double)p.y, pz = (double)p.z;
        double t2  = px * px + py * py + pz * pz;
        double dot = nx * px + ny * py + nz * pz;
        bool inb = ((t1 + t2) - 2.0 * dot) < r2;
        unsigned long long mask = __ballot(inb);
        if (cnt == 0 && mask != 0ull)
            first = base + (int)__builtin_ctzll(mask);
        if (inb) {
            unsigned long long lt = mask & ((1ull << lane) - 1ull);
            int slot = cnt + (int)__popcll(lt);
            if (slot < KK) out[slot] = base + lane;
        }
        cnt += (int)__popcll(mask);
        if (cnt >= KK) break;
    }
    if (cnt < KK && lane >= cnt && lane < KK) out[lane] = first;
}

__global__ __launch_bounds__(256) void group_kernel(const float4* __restrict__ packed,
                                                    const float* __restrict__ new_xyz,
                                                    const float* __restrict__ features,
                                                    const int* __restrict__ idx,
                                                    float* __restrict__ out) {
    int bc = blockIdx.x >> 7;
    int s5 = blockIdx.x & 127;
    int b  = bc / 67;
    int ch = bc - b * 67;
    int s  = (s5 << 5) | ((int)threadIdx.x >> 3);
    int k0 = ((int)threadIdx.x & 7) << 2;

    const int4 jj = *(const int4*)(idx + ((size_t)(b * SS + s) * KK + k0));
    size_t oaddr = ((size_t)bc * SS + s) * KK + k0;

    float4 r;
    if (ch < 3) {
        const float4* pts = packed + (size_t)b * NN;
        float4 p0 = pts[jj.x], p1 = pts[jj.y], p2 = pts[jj.z], p3 = pts[jj.w];
        float nc = new_xyz[(size_t)(b * SS + s) * 3 + ch];
        float a0, a1, a2, a3;
        if (ch == 0)      { a0 = p0.x; a1 = p1.x; a2 = p2.x; a3 = p3.x; }
        else if (ch == 1) { a0 = p0.y; a1 = p1.y; a2 = p2.y; a3 = p3.y; }
        else              { a0 = p0.z; a1 = p1.z; a2 = p2.z; a3 = p3.z; }
        r = make_float4(a0 - nc, a1 - nc, a2 - nc, a3 - nc);
    } else {
        const float* f = features + ((size_t)b * CC + (ch - 3)) * NN;
        r = make_float4(f[jj.x], f[jj.y], f[jj.z], f[jj.w]);
    }
    *(float4*)(out + oaddr) = r;
}

extern "C" void kernel_launch(void* const* d_in, const int* in_sizes, int n_in,
                              void* d_out, int out_size, void* d_ws, size_t ws_size,
                              hipStream_t stream) {
    const float* xyz      = (const float*)d_in[0];   // [B,N,3]
    const float* new_xyz  = (const float*)d_in[1];   // [B,S,3]
    const float* features = (const float*)d_in[2];   // [B,C,N]
    float* out = (float*)d_out;                      // [B,67,S,K]

    float4* packed = (float4*)d_ws;
    int*    idx    = (int*)((char*)d_ws + PACKED_BYTES);
    float*  featT  = (float*)((char*)d_ws + PACKED_BYTES + IDX_BYTES);

    bool fast = ws_size >= PACKED_BYTES + IDX_BYTES + FEATT_BYTES;

    if (fast) {
        prep_kernel<<<64 + BB * (NN / 64), 256, 0, stream>>>(xyz, features, packed, featT);
        fused_kernel<<<BB * SS, 256, 0, stream>>>(packed, new_xyz, featT, out);
    } else {
        prep_kernel<<<64, 256, 0, stream>>>(xyz, features, packed, featT);  // pack only
        ballq_kernel<<<(BB * SS) / 4, 256, 0, stream>>>(packed, new_xyz, idx);
        group_kernel<<<BB * 67 * (SS / 32), 256, 0, stream>>>(packed, new_xyz, features, idx, out);
    }
}

// Round 6
// 58.907 us; speedup vs baseline: 2.0475x; 1.1555x over previous
//
#include <hip/hip_runtime.h>
#include <stdint.h>

// Problem constants (match reference)
#define BB 4
#define NN 16384
#define SS 4096
#define CC 64
#define KK 32
#define R2F 0.04f
#define EPSF 1e-5f   // f32 screen band; f32 d2 abs err bound ~5e-7, 20x margin

// ws layout:
//   [0, 1MB)    packed float4 {x,y,z,|p|^2}
//   [1MB, 3MB)  idx int32 [B,S,K]        (fallback path only)
//   [3MB, 19MB) featT float [B,N,C]
#define PACKED_BYTES ((size_t)BB * NN * sizeof(float4))
#define IDX_BYTES    ((size_t)BB * SS * KK * sizeof(int))
#define FEATT_BYTES  ((size_t)BB * NN * CC * sizeof(float))

// ---------------------------------------------------------------------------
// Kernel 0: prep = pack (blocks 0..63) + transpose (blocks 64..1087).
// pack: xyz -> float4 {x,y,z,|p|^2_f32}  (w used ONLY for the f32 screen).
// transpose: features [B,C,N] -> featT [B,N,C].
// ---------------------------------------------------------------------------
__global__ __launch_bounds__(256) void prep_kernel(const float* __restrict__ xyz,
                                                   const float* __restrict__ features,
                                                   float4* __restrict__ packed,
                                                   float* __restrict__ featT) {
    int blk = blockIdx.x;
    if (blk < 64) {
        for (int i = 0; i < 4; ++i) {
            int p = blk * 1024 + i * 256 + (int)threadIdx.x;
            float x = xyz[(size_t)p * 3 + 0];
            float y = xyz[(size_t)p * 3 + 1];
            float z = xyz[(size_t)p * 3 + 2];
            float w = fmaf(z, z, fmaf(y, y, x * x));
            packed[p] = make_float4(x, y, z, w);
        }
        return;
    }
    blk -= 64;
    int b  = blk >> 8;               // NN/64 = 256 tiles per b
    int n0 = (blk & 255) << 6;
    const float* f = features + (size_t)b * CC * NN;
    for (int i = 0; i < 4; ++i) {
        int e  = (int)threadIdx.x + i * 256;   // 0..1023
        int c4 = e & 15;
        int n  = n0 + (e >> 4);
        float4 v;
        v.x = f[(size_t)(c4 * 4 + 0) * NN + n];
        v.y = f[(size_t)(c4 * 4 + 1) * NN + n];
        v.z = f[(size_t)(c4 * 4 + 2) * NN + n];
        v.w = f[(size_t)(c4 * 4 + 3) * NN + n];
        *(float4*)(featT + ((size_t)b * NN + n) * CC + c4 * 4) = v;
    }
}

// ---------------------------------------------------------------------------
// Kernel 1 (fused v6): block = 4 waves = 4 consecutive centroids (s0..s0+3).
// Phase A: each wave scans ITS centroid independently (no barriers): 64-pt
//   chunks, 1-chunk prefetch, ballot+popc prefix -> first-KK-in-index-order.
//   f32 screen (uses packed.w), f64 recheck only in |d2-R2|<EPS band ->
//   decisions bit-identical to the f64 numpy reference.
// Phase B (x2 passes of 2 centroids, 16KB sfeat reused): stage 64 featT rows
//   (256B dense) into rotation-swizzled LDS, then write 67ch x 2s x 32k as
//   float4 (full 128B lines, 256B contiguous per channel).
// XCD swizzle: 4096 blocks, bijective; XCD x -> b = x/2 (packed prefix +
// featT slice L1/L2-local).
// ---------------------------------------------------------------------------
__global__ __launch_bounds__(256) void fused_kernel(const float4* __restrict__ packed,
                                                    const float* __restrict__ new_xyz,
                                                    const float* __restrict__ featT,
                                                    float* __restrict__ out) {
    __shared__ int    sidx[128];        // [w*32 + slot]
    __shared__ float  sxyz[3][128];
    __shared__ float  snc[12];
    __shared__ float4 sfeat[64][16];    // 16KB, col rotated by (row>>2)&7

    int bid  = blockIdx.x;
    int wgid = (bid & 7) * 512 + (bid >> 3);   // bijective: 4096 % 8 == 0
    int b  = wgid >> 10;
    int s0 = (wgid & 1023) << 2;
    int t = (int)threadIdx.x;
    int w = t >> 6, lane = t & 63;
    int s = s0 + w;

    const float* nc = new_xyz + (size_t)(b * SS + s) * 3;
    const float nxf = nc[0], nyf = nc[1], nzf = nc[2];
    if (lane < 3) snc[w * 3 + lane] = nc[lane];
    const float t1f = fmaf(nzf, nzf, fmaf(nyf, nyf, nxf * nxf));
    const double nx = (double)nxf, ny = (double)nyf, nz = (double)nzf;
    const double t1 = nx * nx + ny * ny + nz * nz;
    const double r2 = 0.2 * 0.2;

    const float4* pts = packed + (size_t)b * NN;

    int cnt = 0;
    int first = 0;
    float4 cur = pts[lane];
    for (int base = 0; base < NN; base += 64) {
        int nb = (base + 64 < NN) ? base + 64 : base;
        float4 nxt = pts[nb + lane];
        float dotf = fmaf(nzf, cur.z, fmaf(nyf, cur.y, nxf * cur.x));
        float d2f  = fmaf(-2.0f, dotf, t1f + cur.w);
        bool inb;
        if (__builtin_fabsf(d2f - R2F) < EPSF) {
            double px = (double)cur.x, py = (double)cur.y, pz = (double)cur.z;
            double t2  = px * px + py * py + pz * pz;
            double dot = nx * px + ny * py + nz * pz;
            inb = ((t1 + t2) - 2.0 * dot) < r2;
        } else {
            inb = d2f < R2F;
        }
        unsigned long long mask = __ballot(inb);
        if (cnt == 0 && mask != 0ull)
            first = base + (int)__builtin_ctzll(mask);
        if (inb) {
            int slot = cnt + (int)__popcll(mask & ((1ull << lane) - 1ull));
            if (slot < KK) {
                int r = w * KK + slot;
                sidx[r] = base + lane;
                sxyz[0][r] = cur.x; sxyz[1][r] = cur.y; sxyz[2][r] = cur.z;
            }
        }
        cnt += (int)__popcll(mask);
        if (cnt >= KK) break;
        cur = nxt;
    }
    if (lane >= cnt && lane < KK) {       // fill tail with first (0 if none)
        float4 p = pts[first];            // broadcast
        int r = w * KK + lane;
        sidx[r] = first;
        sxyz[0][r] = p.x; sxyz[1][r] = p.y; sxyz[2][r] = p.z;
    }
    __syncthreads();

    const size_t cs = (size_t)SS * KK;
    size_t obase = (size_t)(b * 67) * cs + (size_t)s0 * KK;

    for (int pass = 0; pass < 2; ++pass) {
        // stage 64 rows (centroids 2*pass, 2*pass+1): 8 thr/row x 2 float4
        for (int i = 0; i < 2; ++i) {
            int slot = i * 256 + t;            // 0..511
            int rl = slot >> 3;                // local row 0..63
            int q  = slot & 7;
            int rg = pass * 64 + rl;           // global row 0..127
            const float4* src = (const float4*)(featT + ((size_t)b * NN + sidx[rg]) * CC);
            int rot = (rl >> 2) & 7;
            sfeat[rl][(q * 2 + rot) & 15]     = src[q * 2];
            sfeat[rl][(q * 2 + 1 + rot) & 15] = src[q * 2 + 1];
        }
        __syncthreads();
        // write 67ch x 2s x 32k = 1072 float4
        for (int id = t; id < 1072; id += 256) {
            int ch = id >> 4, m = id & 15;
            int sl = m >> 3, k0 = (m & 7) << 2;
            float4 v;
            if (ch < 3) {
                int rb = (pass * 2 + sl) * KK + k0;    // into sxyz[ ][128]
                float nv = snc[(pass * 2 + sl) * 3 + ch];
                v = make_float4(sxyz[ch][rb] - nv, sxyz[ch][rb + 1] - nv,
                                sxyz[ch][rb + 2] - nv, sxyz[ch][rb + 3] - nv);
            } else {
                int c = ch - 3, c4 = c >> 2, cj = c & 3;
                int rl = sl * KK + k0;                 // local row in sfeat
                v.x = ((const float*)&sfeat[rl    ][(c4 + (((rl    ) >> 2) & 7)) & 15])[cj];
                v.y = ((const float*)&sfeat[rl + 1][(c4 + (((rl + 1) >> 2) & 7)) & 15])[cj];
                v.z = ((const float*)&sfeat[rl + 2][(c4 + (((rl + 2) >> 2) & 7)) & 15])[cj];
                v.w = ((const float*)&sfeat[rl + 3][(c4 + (((rl + 3) >> 2) & 7)) & 15])[cj];
            }
            *(float4*)(out + obase + (size_t)ch * cs + pass * 64 + m * 4) = v;
        }
        __syncthreads();   // before sfeat reuse
    }
}

// ---------------------------------------------------------------------------
// Fallback path (ws too small for featT)
// ---------------------------------------------------------------------------
__global__ __launch_bounds__(256) void ballq_kernel(const float4* __restrict__ packed,
                                                    const float* __restrict__ new_xyz,
                                                    int* __restrict__ idx) {
    int wid  = (int)((blockIdx.x * blockDim.x + threadIdx.x) >> 6);
    int lane = (int)(threadIdx.x & 63);
    int b = wid >> 12;
    int s = wid & (SS - 1);

    const float* nc = new_xyz + (size_t)(b * SS + s) * 3;
    const double nx = (double)nc[0], ny = (double)nc[1], nz = (double)nc[2];
    const double t1 = nx * nx + ny * ny + nz * nz;
    const double r2 = 0.2 * 0.2;

    const float4* pts = packed + (size_t)b * NN;
    int* out = idx + (size_t)wid * KK;

    int cnt = 0;
    int first = 0;
    for (int base = 0; base < NN; base += 64) {
        float4 p = pts[base + lane];
        double px = (double)p.x, py = (double)p.y, pz = (double)p.z;
        double t2  = px * px + py * py + pz * pz;
        double dot = nx * px + ny * py + nz * pz;
        bool inb = ((t1 + t2) - 2.0 * dot) < r2;
        unsigned long long mask = __ballot(inb);
        if (cnt == 0 && mask != 0ull)
            first = base + (int)__builtin_ctzll(mask);
        if (inb) {
            unsigned long long lt = mask & ((1ull << lane) - 1ull);
            int slot = cnt + (int)__popcll(lt);
            if (slot < KK) out[slot] = base + lane;
        }
        cnt += (int)__popcll(mask);
        if (cnt >= KK) break;
    }
    if (cnt < KK && lane >= cnt && lane < KK) out[lane] = first;
}

__global__ __launch_bounds__(256) void group_kernel(const float4* __restrict__ packed,
                                                    const float* __restrict__ new_xyz,
                                                    const float* __restrict__ features,
                                                    const int* __restrict__ idx,
                                                    float* __restrict__ out) {
    int bc = blockIdx.x >> 7;
    int s5 = blockIdx.x & 127;
    int b  = bc / 67;
    int ch = bc - b * 67;
    int s  = (s5 << 5) | ((int)threadIdx.x >> 3);
    int k0 = ((int)threadIdx.x & 7) << 2;

    const int4 jj = *(const int4*)(idx + ((size_t)(b * SS + s) * KK + k0));
    size_t oaddr = ((size_t)bc * SS + s) * KK + k0;

    float4 r;
    if (ch < 3) {
        const float4* pts = packed + (size_t)b * NN;
        float4 p0 = pts[jj.x], p1 = pts[jj.y], p2 = pts[jj.z], p3 = pts[jj.w];
        float nc = new_xyz[(size_t)(b * SS + s) * 3 + ch];
        float a0, a1, a2, a3;
        if (ch == 0)      { a0 = p0.x; a1 = p1.x; a2 = p2.x; a3 = p3.x; }
        else if (ch == 1) { a0 = p0.y; a1 = p1.y; a2 = p2.y; a3 = p3.y; }
        else              { a0 = p0.z; a1 = p1.z; a2 = p2.z; a3 = p3.z; }
        r = make_float4(a0 - nc, a1 - nc, a2 - nc, a3 - nc);
    } else {
        const float* f = features + ((size_t)b * CC + (ch - 3)) * NN;
        r = make_float4(f[jj.x], f[jj.y], f[jj.z], f[jj.w]);
    }
    *(float4*)(out + oaddr) = r;
}

extern "C" void kernel_launch(void* const* d_in, const int* in_sizes, int n_in,
                              void* d_out, int out_size, void* d_ws, size_t ws_size,
                              hipStream_t stream) {
    const float* xyz      = (const float*)d_in[0];   // [B,N,3]
    const float* new_xyz  = (const float*)d_in[1];   // [B,S,3]
    const float* features = (const float*)d_in[2];   // [B,C,N]
    float* out = (float*)d_out;                      // [B,67,S,K]

    float4* packed = (float4*)d_ws;
    int*    idx    = (int*)((char*)d_ws + PACKED_BYTES);
    float*  featT  = (float*)((char*)d_ws + PACKED_BYTES + IDX_BYTES);

    bool fast = ws_size >= PACKED_BYTES + IDX_BYTES + FEATT_BYTES;

    if (fast) {
        prep_kernel<<<64 + BB * (NN / 64), 256, 0, stream>>>(xyz, features, packed, featT);
        fused_kernel<<<BB * SS / 4, 256, 0, stream>>>(packed, new_xyz, featT, out);
    } else {
        prep_kernel<<<64, 256, 0, stream>>>(xyz, features, packed, featT);  // pack only
        ballq_kernel<<<(BB * SS) / 4, 256, 0, stream>>>(packed, new_xyz, idx);
        group_kernel<<<BB * 67 * (SS / 32), 256, 0, stream>>>(packed, new_xyz, features, idx, out);
    }
}

// Round 7
// 57.605 us; speedup vs baseline: 2.0937x; 1.0226x over previous
//
#include <hip/hip_runtime.h>
#include <stdint.h>

// Problem constants (match reference)
#define BB 4
#define NN 16384
#define SS 4096
#define CC 64
#define KK 32
#define R2F 0.04f
#define EPSF 1e-5f   // f32 screen band; f32 d2 abs err bound ~5e-7, 20x margin

// ws layout:
//   [0, 1MB)    packed float4 {x,y,z,|p|^2}
//   [1MB, 3MB)  idx int32 [B,S,K]        (fallback path only)
//   [3MB, 19MB) featT float [B,N,C]
#define PACKED_BYTES ((size_t)BB * NN * sizeof(float4))
#define IDX_BYTES    ((size_t)BB * SS * KK * sizeof(int))
#define FEATT_BYTES  ((size_t)BB * NN * CC * sizeof(float))

// ---------------------------------------------------------------------------
// Kernel 0: prep = pack (blocks 0..63) + transpose (blocks 64..1087).
// ---------------------------------------------------------------------------
__global__ __launch_bounds__(256) void prep_kernel(const float* __restrict__ xyz,
                                                   const float* __restrict__ features,
                                                   float4* __restrict__ packed,
                                                   float* __restrict__ featT) {
    int blk = blockIdx.x;
    if (blk < 64) {
        for (int i = 0; i < 4; ++i) {
            int p = blk * 1024 + i * 256 + (int)threadIdx.x;
            float x = xyz[(size_t)p * 3 + 0];
            float y = xyz[(size_t)p * 3 + 1];
            float z = xyz[(size_t)p * 3 + 2];
            float w = fmaf(z, z, fmaf(y, y, x * x));
            packed[p] = make_float4(x, y, z, w);
        }
        return;
    }
    blk -= 64;
    int b  = blk >> 8;               // NN/64 = 256 tiles per b
    int n0 = (blk & 255) << 6;
    const float* f = features + (size_t)b * CC * NN;
    for (int i = 0; i < 4; ++i) {
        int e  = (int)threadIdx.x + i * 256;   // 0..1023
        int c4 = e & 15;
        int n  = n0 + (e >> 4);
        float4 v;
        v.x = f[(size_t)(c4 * 4 + 0) * NN + n];
        v.y = f[(size_t)(c4 * 4 + 1) * NN + n];
        v.z = f[(size_t)(c4 * 4 + 2) * NN + n];
        v.w = f[(size_t)(c4 * 4 + 3) * NN + n];
        *(float4*)(featT + ((size_t)b * NN + n) * CC + c4 * 4) = v;
    }
}

// ---------------------------------------------------------------------------
// Kernel 1 (fused v7): block = 4 waves = 4 consecutive centroids.
// Phase A: per-wave independent scan (no barriers), 2-deep prefetch, f32
//   screen + f64 recheck in |d2-R2|<EPS band (bit-identical to f64 ref).
// Phase B (x2 passes of 2 centroids): stage 64 featT rows into swizzled LDS
//   (col = (c4+row)&15), then per wave-instr ONE ds_read_b128 (wave-uniform
//   c4, lane = row -> full bank spread) + 4 coalesced scalar nt-stores
//   (64 lanes x 4B = 256B contiguous per channel plane).
// Nontemporal stores keep the 137MB stream out of L2 so packed+featT stay
// XCD-L2-resident.
// ---------------------------------------------------------------------------
__global__ __launch_bounds__(256) void fused_kernel(const float4* __restrict__ packed,
                                                    const float* __restrict__ new_xyz,
                                                    const float* __restrict__ featT,
                                                    float* __restrict__ out) {
    __shared__ int    sidx[128];        // [centroid_local*32 + slot]
    __shared__ float  sxyz[3][128];
    __shared__ float  snc[12];
    __shared__ float4 sfeat[64][16];    // 16KB; col = (c4 + row) & 15

    int bid  = blockIdx.x;
    int wgid = (bid & 7) * 512 + (bid >> 3);   // bijective: 4096 % 8 == 0
    int b  = wgid >> 10;
    int s0 = (wgid & 1023) << 2;
    int t = (int)threadIdx.x;
    int w = t >> 6, lane = t & 63;
    int s = s0 + w;

    const float* nc = new_xyz + (size_t)(b * SS + s) * 3;
    const float nxf = nc[0], nyf = nc[1], nzf = nc[2];
    if (lane < 3) snc[w * 3 + lane] = nc[lane];
    const float t1f = fmaf(nzf, nzf, fmaf(nyf, nyf, nxf * nxf));
    const double nx = (double)nxf, ny = (double)nyf, nz = (double)nzf;
    const double t1 = nx * nx + ny * ny + nz * nz;
    const double r2 = 0.2 * 0.2;

    const float4* pts = packed + (size_t)b * NN;

    // ---- Phase A: scan (per-wave independent, 2-deep prefetch) ----
    int cnt = 0;
    int first = 0;
    float4 c0 = pts[lane];
    float4 c1 = pts[64 + lane];
    for (int base = 0; base < NN; base += 64) {
        int nb = (base + 128 < NN) ? (base + 128) : base;
        float4 c2 = pts[nb + lane];
        float dotf = fmaf(nzf, c0.z, fmaf(nyf, c0.y, nxf * c0.x));
        float d2f  = fmaf(-2.0f, dotf, t1f + c0.w);
        bool inb;
        if (__builtin_fabsf(d2f - R2F) < EPSF) {
            double px = (double)c0.x, py = (double)c0.y, pz = (double)c0.z;
            double t2  = px * px + py * py + pz * pz;
            double dot = nx * px + ny * py + nz * pz;
            inb = ((t1 + t2) - 2.0 * dot) < r2;
        } else {
            inb = d2f < R2F;
        }
        unsigned long long mask = __ballot(inb);
        if (cnt == 0 && mask != 0ull)
            first = base + (int)__builtin_ctzll(mask);
        if (inb) {
            int slot = cnt + (int)__popcll(mask & ((1ull << lane) - 1ull));
            if (slot < KK) {
                int r = w * KK + slot;
                sidx[r] = base + lane;
                sxyz[0][r] = c0.x; sxyz[1][r] = c0.y; sxyz[2][r] = c0.z;
            }
        }
        cnt += (int)__popcll(mask);
        if (cnt >= KK) break;
        c0 = c1; c1 = c2;
    }
    if (lane >= cnt && lane < KK) {       // fill tail with first (0 if none)
        float4 p = pts[first];            // broadcast
        int r = w * KK + lane;
        sidx[r] = first;
        sxyz[0][r] = p.x; sxyz[1][r] = p.y; sxyz[2][r] = p.z;
    }
    __syncthreads();

    // ---- Phase B: stage + write, 2 centroids per pass ----
    const size_t cs = (size_t)SS * KK;
    size_t obase = (size_t)(b * 67) * cs + (size_t)s0 * KK;

    for (int pass = 0; pass < 2; ++pass) {
        // stage 64 rows: 8 threads/row x 2 float4 (256B dense per row)
        for (int i = 0; i < 2; ++i) {
            int slot = i * 256 + t;            // 0..511
            int rl = slot >> 3;                // local row 0..63
            int q  = slot & 7;
            const float4* src = (const float4*)(featT +
                ((size_t)b * NN + sidx[pass * 64 + rl]) * CC);
            float4 v0 = src[q * 2];
            float4 v1 = src[q * 2 + 1];
            sfeat[rl][(q * 2     + rl) & 15] = v0;
            sfeat[rl][(q * 2 + 1 + rl) & 15] = v1;
        }
        __syncthreads();

        float* pbase = out + obase + (size_t)pass * 64;
        // feature channels: wave w covers c4 = w*4 .. w*4+3
        for (int cc = 0; cc < 4; ++cc) {
            int c4 = w * 4 + cc;                       // wave-uniform
            float4 v = sfeat[lane][(c4 + lane) & 15];  // one ds_read_b128
            float* pl = pbase + lane;
            __builtin_nontemporal_store(v.x, pl + (size_t)(3 + c4 * 4 + 0) * cs);
            __builtin_nontemporal_store(v.y, pl + (size_t)(3 + c4 * 4 + 1) * cs);
            __builtin_nontemporal_store(v.z, pl + (size_t)(3 + c4 * 4 + 2) * cs);
            __builtin_nontemporal_store(v.w, pl + (size_t)(3 + c4 * 4 + 3) * cs);
        }
        // xyz channels (3 x 64), waves 0..2
        if (t < 192) {
            int ch = t >> 6, rl = t & 63;
            float v = sxyz[ch][pass * 64 + rl] - snc[(2 * pass + (rl >> 5)) * 3 + ch];
            __builtin_nontemporal_store(v, pbase + (size_t)ch * cs + rl);
        }
        __syncthreads();   // before sfeat reuse
    }
}

// ---------------------------------------------------------------------------
// Fallback path (ws too small for featT)
// ---------------------------------------------------------------------------
__global__ __launch_bounds__(256) void ballq_kernel(const float4* __restrict__ packed,
                                                    const float* __restrict__ new_xyz,
                                                    int* __restrict__ idx) {
    int wid  = (int)((blockIdx.x * blockDim.x + threadIdx.x) >> 6);
    int lane = (int)(threadIdx.x & 63);
    int b = wid >> 12;
    int s = wid & (SS - 1);

    const float* nc = new_xyz + (size_t)(b * SS + s) * 3;
    const double nx = (double)nc[0], ny = (double)nc[1], nz = (double)nc[2];
    const double t1 = nx * nx + ny * ny + nz * nz;
    const double r2 = 0.2 * 0.2;

    const float4* pts = packed + (size_t)b * NN;
    int* out = idx + (size_t)wid * KK;

    int cnt = 0;
    int first = 0;
    for (int base = 0; base < NN; base += 64) {
        float4 p = pts[base + lane];
        double px = (double)p.x, py = (double)p.y, pz = (double)p.z;
        double t2  = px * px + py * py + pz * pz;
        double dot = nx * px + ny * py + nz * pz;
        bool inb = ((t1 + t2) - 2.0 * dot) < r2;
        unsigned long long mask = __ballot(inb);
        if (cnt == 0 && mask != 0ull)
            first = base + (int)__builtin_ctzll(mask);
        if (inb) {
            unsigned long long lt = mask & ((1ull << lane) - 1ull);
            int slot = cnt + (int)__popcll(lt);
            if (slot < KK) out[slot] = base + lane;
        }
        cnt += (int)__popcll(mask);
        if (cnt >= KK) break;
    }
    if (cnt < KK && lane >= cnt && lane < KK) out[lane] = first;
}

__global__ __launch_bounds__(256) void group_kernel(const float4* __restrict__ packed,
                                                    const float* __restrict__ new_xyz,
                                                    const float* __restrict__ features,
                                                    const int* __restrict__ idx,
                                                    float* __restrict__ out) {
    int bc = blockIdx.x >> 7;
    int s5 = blockIdx.x & 127;
    int b  = bc / 67;
    int ch = bc - b * 67;
    int s  = (s5 << 5) | ((int)threadIdx.x >> 3);
    int k0 = ((int)threadIdx.x & 7) << 2;

    const int4 jj = *(const int4*)(idx + ((size_t)(b * SS + s) * KK + k0));
    size_t oaddr = ((size_t)bc * SS + s) * KK + k0;

    float4 r;
    if (ch < 3) {
        const float4* pts = packed + (size_t)b * NN;
        float4 p0 = pts[jj.x], p1 = pts[jj.y], p2 = pts[jj.z], p3 = pts[jj.w];
        float nc = new_xyz[(size_t)(b * SS + s) * 3 + ch];
        float a0, a1, a2, a3;
        if (ch == 0)      { a0 = p0.x; a1 = p1.x; a2 = p2.x; a3 = p3.x; }
        else if (ch == 1) { a0 = p0.y; a1 = p1.y; a2 = p2.y; a3 = p3.y; }
        else              { a0 = p0.z; a1 = p1.z; a2 = p2.z; a3 = p3.z; }
        r = make_float4(a0 - nc, a1 - nc, a2 - nc, a3 - nc);
    } else {
        const float* f = features + ((size_t)b * CC + (ch - 3)) * NN;
        r = make_float4(f[jj.x], f[jj.y], f[jj.z], f[jj.w]);
    }
    *(float4*)(out + oaddr) = r;
}

extern "C" void kernel_launch(void* const* d_in, const int* in_sizes, int n_in,
                              void* d_out, int out_size, void* d_ws, size_t ws_size,
                              hipStream_t stream) {
    const float* xyz      = (const float*)d_in[0];   // [B,N,3]
    const float* new_xyz  = (const float*)d_in[1];   // [B,S,3]
    const float* features = (const float*)d_in[2];   // [B,C,N]
    float* out = (float*)d_out;                      // [B,67,S,K]

    float4* packed = (float4*)d_ws;
    int*    idx    = (int*)((char*)d_ws + PACKED_BYTES);
    float*  featT  = (float*)((char*)d_ws + PACKED_BYTES + IDX_BYTES);

    bool fast = ws_size >= PACKED_BYTES + IDX_BYTES + FEATT_BYTES;

    if (fast) {
        prep_kernel<<<64 + BB * (NN / 64), 256, 0, stream>>>(xyz, features, packed, featT);
        fused_kernel<<<BB * SS / 4, 256, 0, stream>>>(packed, new_xyz, featT, out);
    } else {
        prep_kernel<<<64, 256, 0, stream>>>(xyz, features, packed, featT);  // pack only
        ballq_kernel<<<(BB * SS) / 4, 256, 0, stream>>>(packed, new_xyz, idx);
        group_kernel<<<BB * 67 * (SS / 32), 256, 0, stream>>>(packed, new_xyz, features, idx, out);
    }
}